// Round 6
// baseline (178.764 us; speedup 1.0000x reference)
//
#include <hip/hip_runtime.h>

#define BINS        4096
#define NIMG        64
#define IMG_ELEMS   (512*512)
#define EMAX        6.5f
#define BPI         32
#define K1_THREADS  256
#define CHUNK       (IMG_ELEMS/BPI)     // 8192 elems per K1 block
#define GRID1       (NIMG*BPI)          // 2048
#define K2B_THREADS 1024

typedef unsigned int u32;
typedef unsigned long long u64;

// ---------------- K1: count-only LDS histogram (real) ----------------
// 2048 blocks x 256 thr; per thread exactly 8 float4-pairs, all 16 loads
// issued before use. Packed counts (pos<<16|neg), chunk=8192 fits u16.
__global__ __launch_bounds__(K1_THREADS, 4)
void lovasz_hist(const float* __restrict__ pred, const float* __restrict__ tgt,
                 u32* __restrict__ regions, u32* __restrict__ Pblk) {
    __shared__ u32 cnt[BINS];
    __shared__ u32 pw[K1_THREADS/64];
    const int bx  = blockIdx.x;
    const int img = bx >> 5, sub = bx & 31;
    const int tid = threadIdx.x;

    for (int i = tid; i < BINS; i += K1_THREADS) cnt[i] = 0u;
    __syncthreads();

    const size_t base = (size_t)img * IMG_ELEMS + (size_t)sub * CHUNK;
    const float4* p4 = (const float4*)(pred + base);
    const float4* t4 = (const float4*)(tgt + base);
    const float scale = (float)BINS / EMAX;

    float4 pv[8], tv[8];
    #pragma unroll
    for (int k = 0; k < 8; ++k) pv[k] = p4[tid + k * K1_THREADS];
    #pragma unroll
    for (int k = 0; k < 8; ++k) tv[k] = t4[tid + k * K1_THREADS];

    u32 posc = 0;
    #pragma unroll
    for (int k = 0; k < 8; ++k) {
        float pa[4] = {pv[k].x, pv[k].y, pv[k].z, pv[k].w};
        float ta[4] = {tv[k].x, tv[k].y, tv[k].z, tv[k].w};
        #pragma unroll
        for (int q = 0; q < 4; ++q) {
            bool pos = ta[q] > 0.5f;
            posc += pos ? 1u : 0u;
            float e = pos ? (1.f - pa[q]) : (1.f + pa[q]);
            if (e > 0.f) {
                int b = (int)(e * scale); if (b > BINS - 1) b = BINS - 1;
                atomicAdd(&cnt[b], pos ? 0x10000u : 1u);
            }
        }
    }
    for (int off = 32; off; off >>= 1) posc += __shfl_down(posc, off, 64);
    if ((tid & 63) == 0) pw[tid >> 6] = posc;
    __syncthreads();
    if (tid == 0) {
        u32 s = 0;
        #pragma unroll
        for (int w = 0; w < K1_THREADS/64; ++w) s += pw[w];
        Pblk[bx] = s;
    }
    u32* reg = regions + (size_t)bx * BINS;
    for (int i = tid; i < BINS; i += K1_THREADS) reg[i] = cnt[i];
}

// ---------------- probeA: loads + math, NO LDS histogram ----------------
__global__ __launch_bounds__(K1_THREADS, 4)
void probeA_noatomic(const float* __restrict__ pred, const float* __restrict__ tgt,
                     u32* __restrict__ sink) {
    const int bx  = blockIdx.x;
    const int img = bx >> 5, sub = bx & 31;
    const int tid = threadIdx.x;
    const size_t base = (size_t)img * IMG_ELEMS + (size_t)sub * CHUNK;
    const float4* p4 = (const float4*)(pred + base);
    const float4* t4 = (const float4*)(tgt + base);
    const float scale = (float)BINS / EMAX;

    float4 pv[8], tv[8];
    #pragma unroll
    for (int k = 0; k < 8; ++k) pv[k] = p4[tid + k * K1_THREADS];
    #pragma unroll
    for (int k = 0; k < 8; ++k) tv[k] = t4[tid + k * K1_THREADS];

    u32 acc = 0;
    #pragma unroll
    for (int k = 0; k < 8; ++k) {
        float pa[4] = {pv[k].x, pv[k].y, pv[k].z, pv[k].w};
        float ta[4] = {tv[k].x, tv[k].y, tv[k].z, tv[k].w};
        #pragma unroll
        for (int q = 0; q < 4; ++q) {
            bool pos = ta[q] > 0.5f;
            float e = pos ? (1.f - pa[q]) : (1.f + pa[q]);
            if (e > 0.f) {
                int b = (int)(e * scale); if (b > BINS - 1) b = BINS - 1;
                acc += (u32)b + (pos ? 0x10000u : 1u);   // same data deps as atomic path
            }
        }
    }
    for (int off = 32; off; off >>= 1) acc += __shfl_down(acc, off, 64);
    if ((tid & 63) == 0) sink[bx * 4 + (tid >> 6)] = acc;
}

// ---------------- probeB: LDS-atomic pattern, NO global loads ----------------
__global__ __launch_bounds__(K1_THREADS, 4)
void probeB_nomem(u32* __restrict__ sink) {
    __shared__ u32 cnt[BINS];
    const int bx  = blockIdx.x;
    const int tid = threadIdx.x;
    for (int i = tid; i < BINS; i += K1_THREADS) cnt[i] = 0u;
    __syncthreads();

    u32 x = (u32)(bx * K1_THREADS + tid) * 2654435761u + 12345u;
    #pragma unroll
    for (int k = 0; k < 32; ++k) {                 // 32 scattered ds_adds / thread
        x = x * 1664525u + 1013904223u;
        u32 b = (x >> 8) & (BINS - 1);
        atomicAdd(&cnt[b], (x & 1u) ? 0x10000u : 1u);
    }
    __syncthreads();
    u32 acc = 0;
    for (int i = tid; i < BINS; i += K1_THREADS) acc ^= cnt[i];
    for (int off = 32; off; off >>= 1) acc ^= __shfl_down(acc, off, 64);
    if ((tid & 63) == 0) sink[bx * 4 + (tid >> 6)] = acc;
}

// ---------------- reduce + loss (as R5, adapted to BPI=32) ----------------
__global__ __launch_bounds__(256, 8)
void lovasz_reduce(const u32* __restrict__ regions, u32* __restrict__ agg) {
    const int blk = blockIdx.x;                    // NIMG*16
    const int img = blk >> 4, c = blk & 15;
    const int bin = c * 256 + threadIdx.x;
    const u32* base = regions + (size_t)img * BPI * BINS + bin;
    u32 cp = 0, cn = 0;
    #pragma unroll 8
    for (int s = 0; s < BPI; ++s) {
        u32 v = base[(size_t)s * BINS];
        cp += v >> 16;
        cn += v & 0xFFFFu;
    }
    agg[(size_t)img * 2 * BINS + bin]        = cp;
    agg[(size_t)img * 2 * BINS + BINS + bin] = cn;
}

__global__ __launch_bounds__(K2B_THREADS, 2)
void lovasz_loss(const u32* __restrict__ agg, const u32* __restrict__ Pblk,
                 float* __restrict__ out) {
    __shared__ u64    wtot[16];
    __shared__ u64    wsuf[16];
    __shared__ double red[16];
    __shared__ u32    Psh;
    const int img = blockIdx.x, tid = threadIdx.x;
    const int lane = tid & 63, wid = tid >> 6;
    const int b0 = tid * 4;

    uint4 v0 = *(const uint4*)(agg + (size_t)img * 2 * BINS + b0);
    uint4 v1 = *(const uint4*)(agg + (size_t)img * 2 * BINS + BINS + b0);

    u32 pc = (tid < BPI) ? Pblk[img * BPI + tid] : 0u;
    if (wid == 0) {
        for (int off = 16; off; off >>= 1) pc += __shfl_down(pc, off, 64);
        if (lane == 0) Psh = pc;
    }

    u32 cp[4] = {v0.x, v0.y, v0.z, v0.w};
    u32 cn[4] = {v1.x, v1.y, v1.z, v1.w};
    u64 own = ((u64)(cp[0]+cp[1]+cp[2]+cp[3]) << 32) | (u64)(cn[0]+cn[1]+cn[2]+cn[3]);

    u64 x = own;
    #pragma unroll
    for (int off = 1; off < 64; off <<= 1) {
        u64 v = __shfl_down(x, off, 64);
        if (lane + off < 64) x += v;
    }
    if (lane == 0) wtot[wid] = x;
    __syncthreads();
    if (tid < 16) {
        u64 w = wtot[tid];
        #pragma unroll
        for (int off = 1; off < 16; off <<= 1) {
            u64 v = __shfl_down(w, off, 64);
            if (tid + off < 16) w += v;
        }
        wsuf[tid] = w;
    }
    __syncthreads();
    u64 above = (x - own) + ((wid < 15) ? wsuf[wid + 1] : 0ull);

    const double P = (double)Psh;
    double p_above = (double)(u32)(above >> 32);
    double n_above = (double)(u32)(above & 0xFFFFFFFFull);
    const double binw = (double)EMAX / (double)BINS;
    double acc = 0.0;
    #pragma unroll
    for (int j = 3; j >= 0; --j) {
        double a = (double)cp[j], c = (double)cn[j];
        double Pn = P + n_above;
        double ctr = ((double)(b0 + j) + 0.5) * binw;
        if (Pn > 0.0) {
            acc += a * ctr / Pn
                 + c * ctr * (P - p_above - a) / (Pn * (Pn + c));
        }
        p_above += a; n_above += c;
    }
    for (int off = 32; off; off >>= 1) acc += __shfl_down(acc, off, 64);
    if (lane == 0) red[wid] = acc;
    __syncthreads();
    if (tid == 0) {
        double tot = 0.0;
        #pragma unroll
        for (int w = 0; w < 16; ++w) tot += red[w];
        atomicAdd(out, (float)(tot / (double)NIMG));
    }
}

extern "C" void kernel_launch(void* const* d_in, const int* in_sizes, int n_in,
                              void* d_out, int out_size, void* d_ws, size_t ws_size,
                              hipStream_t stream) {
    const float* pred = (const float*)d_in[0];
    const float* tgt  = (const float*)d_in[1];

    u32* regions = (u32*)d_ws;                                         // 32 MB
    u32* agg     = (u32*)((char*)d_ws + (size_t)GRID1 * BINS * 4);     // 2 MB
    u32* Pblk    = (u32*)((char*)agg + (size_t)NIMG * 2 * BINS * 4);   // 8 KB
    u32* sink    = (u32*)((char*)Pblk + (size_t)GRID1 * 4);            // 32 KB

    hipMemsetAsync(d_out, 0, sizeof(float), stream);

    lovasz_hist  <<<GRID1,     K1_THREADS,  0, stream>>>(pred, tgt, regions, Pblk);
    lovasz_reduce<<<NIMG * 16, 256,         0, stream>>>(regions, agg);
    lovasz_loss  <<<NIMG,      K2B_THREADS, 0, stream>>>(agg, Pblk, (float*)d_out);

    // ---- ablation probes (scratch-only; per-dispatch timing via rocprof) ----
    probeA_noatomic<<<GRID1, K1_THREADS, 0, stream>>>(pred, tgt, sink);
    probeB_nomem   <<<GRID1, K1_THREADS, 0, stream>>>(sink + GRID1 * 4);
}

// Round 7
// 156.039 us; speedup vs baseline: 1.1456x; 1.1456x over previous
//
#include <hip/hip_runtime.h>

#define BINS        2048
#define NIMG        64
#define IMG_ELEMS   (512*512)
#define EMAX        6.5f
#define BPI         32
#define K1_THREADS  512
#define CHUNK       (IMG_ELEMS/BPI)     // 8192 elems per K1 block
#define GRID1       (NIMG*BPI)          // 2048 blocks
#define K2_THREADS  512

typedef unsigned int u32;
typedef unsigned long long u64;

// Count-only LDS histogram, packed (pos<<16 | neg); chunk=8192 fits u16.
// BINS=2048: LDS 8.25KB/block -> 32 waves/CU; error sums reconstructed as
// count*bin_center in K2 (residual ~3e-7 of output; 0.0 measured at 4096).
__global__ __launch_bounds__(K1_THREADS, 8)
void lovasz_hist(const float* __restrict__ pred, const float* __restrict__ tgt,
                 u32* __restrict__ regions, u32* __restrict__ Pblk) {
    __shared__ u32 cnt[BINS];
    __shared__ u32 pw[K1_THREADS/64];
    const int bx  = blockIdx.x;
    const int img = bx >> 5, sub = bx & 31;
    const int tid = threadIdx.x;

    {   // one ds_write_b128 per thread
        uint4 z; z.x = z.y = z.z = z.w = 0u;
        ((uint4*)cnt)[tid] = z;
    }
    __syncthreads();

    const size_t base = (size_t)img * IMG_ELEMS + (size_t)sub * CHUNK;
    const float4* p4 = (const float4*)(pred + base);
    const float4* t4 = (const float4*)(tgt + base);
    const float scale = (float)BINS / EMAX;

    // 4+4 float4 pairs, all 8 loads issued before any use (32 VGPR of data)
    float4 pv[4], tv[4];
    #pragma unroll
    for (int k = 0; k < 4; ++k) pv[k] = p4[tid + k * K1_THREADS];
    #pragma unroll
    for (int k = 0; k < 4; ++k) tv[k] = t4[tid + k * K1_THREADS];

    u32 posc = 0;
    #pragma unroll
    for (int k = 0; k < 4; ++k) {
        float pa[4] = {pv[k].x, pv[k].y, pv[k].z, pv[k].w};
        float ta[4] = {tv[k].x, tv[k].y, tv[k].z, tv[k].w};
        #pragma unroll
        for (int q = 0; q < 4; ++q) {
            bool pos = ta[q] > 0.5f;
            posc += pos ? 1u : 0u;                  // P counts ALL positives
            float e = pos ? (1.f - pa[q]) : (1.f + pa[q]);
            if (e > 0.f) {                          // relu gate: e<=0 contributes 0
                int b = (int)(e * scale); if (b > BINS - 1) b = BINS - 1;
                atomicAdd(&cnt[b], pos ? 0x10000u : 1u);
            }
        }
    }
    for (int off = 32; off; off >>= 1) posc += __shfl_down(posc, off, 64);
    if ((tid & 63) == 0) pw[tid >> 6] = posc;
    __syncthreads();
    if (tid == 0) {
        u32 s = 0;
        #pragma unroll
        for (int w = 0; w < K1_THREADS/64; ++w) s += pw[w];
        Pblk[bx] = s;                               // plain store, no memset
    }
    // flush: one ds_read_b128 + global dwordx4 per thread
    u32* reg = regions + (size_t)bx * BINS;
    ((uint4*)reg)[tid] = ((const uint4*)cnt)[tid];
}

// One block per image: aggregate 32 sub-hists (independent uint4 loads),
// shfl-based suffix scan over bins (descending e), fp64 closed form.
__global__ __launch_bounds__(K2_THREADS, 2)
void lovasz_loss(const u32* __restrict__ regions, const u32* __restrict__ Pblk,
                 float* __restrict__ out) {
    __shared__ u64    wtot[8];
    __shared__ u64    wsuf[8];
    __shared__ double red[8];
    __shared__ u32    Psh;
    const int img = blockIdx.x, tid = threadIdx.x;
    const int lane = tid & 63, wid = tid >> 6;
    const int b0 = tid * 4;                          // 512*4 == 2048 bins

    u32 cp[4] = {0,0,0,0}, cn[4] = {0,0,0,0};
    const u32* base = regions + (size_t)img * BPI * BINS;
    #pragma unroll
    for (int s = 0; s < BPI; ++s) {
        uint4 v = *(const uint4*)(base + (size_t)s * BINS + b0);
        cp[0] += v.x >> 16;     cp[1] += v.y >> 16;     cp[2] += v.z >> 16;     cp[3] += v.w >> 16;
        cn[0] += v.x & 0xFFFFu; cn[1] += v.y & 0xFFFFu; cn[2] += v.z & 0xFFFFu; cn[3] += v.w & 0xFFFFu;
    }

    u32 pc = (tid < BPI) ? Pblk[img * BPI + tid] : 0u;
    if (wid == 0) {
        for (int off = 32; off; off >>= 1) pc += __shfl_down(pc, off, 64);
        if (lane == 0) Psh = pc;
    }

    u64 own = ((u64)(cp[0]+cp[1]+cp[2]+cp[3]) << 32) | (u64)(cn[0]+cn[1]+cn[2]+cn[3]);

    // intra-wave inclusive suffix scan (bins ascend with tid; "above" = higher tid)
    u64 x = own;
    #pragma unroll
    for (int off = 1; off < 64; off <<= 1) {
        u64 v = __shfl_down(x, off, 64);
        if (lane + off < 64) x += v;
    }
    if (lane == 0) wtot[wid] = x;
    __syncthreads();
    if (tid < 8) {
        u64 w = wtot[tid];
        #pragma unroll
        for (int off = 1; off < 8; off <<= 1) {
            u64 v = __shfl_down(w, off, 64);
            if (tid + off < 8) w += v;
        }
        wsuf[tid] = w;                               // inclusive suffix over waves
    }
    __syncthreads();
    u64 above = (x - own) + ((wid < 7) ? wsuf[wid + 1] : 0ull);

    const double P = (double)Psh;
    double p_above = (double)(u32)(above >> 32);
    double n_above = (double)(u32)(above & 0xFFFFFFFFull);
    const double binw = (double)EMAX / (double)BINS;
    double acc = 0.0;
    #pragma unroll
    for (int j = 3; j >= 0; --j) {                   // own bins, descending e
        double a = (double)cp[j], c = (double)cn[j];
        double Pn = P + n_above;
        double ctr = ((double)(b0 + j) + 0.5) * binw;
        if (Pn > 0.0) {
            // positives first: a * ctr / Pn ; negatives (rank-exact telescoped):
            acc += a * ctr / Pn
                 + c * ctr * (P - p_above - a) / (Pn * (Pn + c));
        }
        p_above += a; n_above += c;
    }
    for (int off = 32; off; off >>= 1) acc += __shfl_down(acc, off, 64);
    if (lane == 0) red[wid] = acc;
    __syncthreads();
    if (tid == 0) {
        double tot = 0.0;
        #pragma unroll
        for (int w = 0; w < 8; ++w) tot += red[w];
        atomicAdd(out, (float)(tot / (double)NIMG));
    }
}

extern "C" void kernel_launch(void* const* d_in, const int* in_sizes, int n_in,
                              void* d_out, int out_size, void* d_ws, size_t ws_size,
                              hipStream_t stream) {
    const float* pred = (const float*)d_in[0];
    const float* tgt  = (const float*)d_in[1];

    u32* regions = (u32*)d_ws;                                      // 2048 x 8KB = 16 MB
    u32* Pblk    = (u32*)((char*)d_ws + (size_t)GRID1 * BINS * 4);  // 8 KB

    hipMemsetAsync(d_out, 0, sizeof(float), stream);

    lovasz_hist<<<GRID1, K1_THREADS, 0, stream>>>(pred, tgt, regions, Pblk);
    lovasz_loss<<<NIMG,  K2_THREADS, 0, stream>>>(regions, Pblk, (float*)d_out);
}